// Round 7
// baseline (1439.114 us; speedup 1.0000x reference)
//
#include <hip/hip_runtime.h>
#include <float.h>

#define DIMC 384
#define NHC 6
#define DHC 64
#define INNERC 384
#define HIDC 1536
#define S_TOT 1600
#define QBLK 16
#define CAPC 64
#define SAK 832     // first key chunk (52 tiles of 16)
#define SBK 768     // second key chunk (48 tiles)
#define SPA 840     // score pitch (u16): 1680B/row -> rows offset by 4 banks

typedef unsigned short u16;
typedef __attribute__((ext_vector_type(8))) short bf16x8;
typedef __attribute__((ext_vector_type(4))) float f32x4;

__device__ __forceinline__ u16 f2bf(float x){
  unsigned u = __float_as_uint(x);
  return (u16)((u + 0x7FFFu + ((u >> 16) & 1u)) >> 16);
}
__device__ __forceinline__ float bf2f(u16 h){
  return __uint_as_float(((unsigned)h) << 16);
}
__device__ __forceinline__ int sortkey(u16 u){
  return (u & 0x8000) ? (int)(u ^ 0xFFFF) : (int)(u | 0x8000);
}
__device__ __forceinline__ u16 invkey(int k){
  return (k & 0x8000) ? (u16)(k & 0x7FFF) : (u16)(k ^ 0xFFFF);
}
__device__ __forceinline__ float waveReduceSumF(float v){
  #pragma unroll
  for (int o = 32; o >= 1; o >>= 1) v += __shfl_xor(v, o);
  return v;
}

// ---------------- copy ----------------
__global__ void copy_kernel(const float* __restrict__ in, float* __restrict__ out, int n){
  int i = blockIdx.x * 256 + threadIdx.x;
  if (i < n) out[i] = in[i];
}

// ---------------- bucket table ----------------
__global__ void buck_kernel(const int* __restrict__ Wp, unsigned char* __restrict__ buck){
  int q = blockIdx.x;
  int Wv = *Wp;
  int qv = q / Wv, qh = q % Wv;
  for (int k = threadIdx.x; k < S_TOT; k += 256){
    int kv = k / Wv, kh = k % Wv;
    int dv = kv - qv, dh = kh - qh;
    int man = (dv < 0 ? -dv : dv) + (dh < 0 ? -dh : dh);
    unsigned char bb = (man <= 3) ? (unsigned char)((dv + 3) * 7 + (dh + 3)) : 0;
    buck[(size_t)q * S_TOT + k] = bb;
  }
}

// ---------------- fused transpose+convert for all 4 layer weights ----------------
struct TC4Args {
  const float *in0, *in1, *in2, *in3;
  u16 *out0, *out1, *out2, *out3;
};
__global__ __launch_bounds__(256) void tconv4_kernel(TC4Args a){
  int b = blockIdx.x;
  const float* in; u16* out; int K, N, t;
  if (b < 432)      { in = a.in0; out = a.out0; K = 384;  N = 1152; t = b; }
  else if (b < 576) { in = a.in1; out = a.out1; K = 384;  N = 384;  t = b - 432; }
  else if (b < 1152){ in = a.in2; out = a.out2; K = 384;  N = 1536; t = b - 576; }
  else              { in = a.in3; out = a.out3; K = 1536; N = 384;  t = b - 1152; }
  int nx = N >> 5;
  int bx = t % nx, by = t / nx;
  __shared__ float tt[32][33];
  int tx = threadIdx.x & 31, ty = threadIdx.x >> 5;
  int k0 = by * 32, n0 = bx * 32;
  #pragma unroll
  for (int i = 0; i < 4; ++i)
    tt[ty + i * 8][tx] = in[(size_t)(k0 + ty + i * 8) * N + n0 + tx];
  __syncthreads();
  #pragma unroll
  for (int i = 0; i < 4; ++i)
    out[(size_t)(n0 + ty + i * 8) * K + k0 + tx] = f2bf(tt[tx][ty + i * 8]);
}

// ---------------- LayerNorm -> bf16 ----------------
__global__ __launch_bounds__(128) void ln_kernel(const float* __restrict__ in,
                                                 const float* __restrict__ g,
                                                 const float* __restrict__ b,
                                                 u16* __restrict__ out){
  int row = blockIdx.x;
  int tid = threadIdx.x;
  const float* rp = in + (size_t)row * DIMC;
  float x0 = rp[tid], x1 = rp[tid + 128], x2 = rp[tid + 256];
  float s  = x0 + x1 + x2;
  float sq = x0 * x0 + x1 * x1 + x2 * x2;
  __shared__ float scr0[2], scr1[2];
  s  = waveReduceSumF(s);
  sq = waveReduceSumF(sq);
  int wid = tid >> 6;
  if ((tid & 63) == 0){ scr0[wid] = s; scr1[wid] = sq; }
  __syncthreads();
  float S1 = scr0[0] + scr0[1];
  float S2 = scr1[0] + scr1[1];
  float mean = S1 * (1.f / DIMC);
  float var  = S2 * (1.f / DIMC) - mean * mean;
  float inv  = rsqrtf(var + 1e-5f);
  u16* op = out + (size_t)row * DIMC;
  op[tid]       = f2bf((x0 - mean) * inv * g[tid]       + b[tid]);
  op[tid + 128] = f2bf((x1 - mean) * inv * g[tid + 128] + b[tid + 128]);
  op[tid + 256] = f2bf((x2 - mean) * inv * g[tid + 256] + b[tid + 256]);
}

// ---------------- bf16 MFMA GEMM ----------------
template<int ACT, bool OUT_BF16, bool HAS_BIAS, bool HAS_RES>
__global__ __launch_bounds__(256) void gemm_bf16(const u16* __restrict__ A,
                                                 const u16* __restrict__ Bt,
                                                 const float* __restrict__ bias,
                                                 const float* __restrict__ res,
                                                 void* __restrict__ Cout,
                                                 int M, int N, int K){
  __shared__ u16 As[64][40];
  __shared__ u16 Bs[64][40];
  const int tid = threadIdx.x, lane = tid & 63, wid = tid >> 6;
  const int m0 = blockIdx.y * 64, n0 = blockIdx.x * 64;
  const int wr = (wid >> 1) * 32, wc = (wid & 1) * 32;
  const int sr = tid >> 2, sc8 = (tid & 3) * 8;
  const int frow = lane & 15, fkc = lane >> 4;

  f32x4 acc[2][2] = {};
  for (int k0 = 0; k0 < K; k0 += 32){
    bf16x8 av = *(const bf16x8*)(A  + (size_t)(m0 + sr) * K + k0 + sc8);
    bf16x8 bv = *(const bf16x8*)(Bt + (size_t)(n0 + sr) * K + k0 + sc8);
    __syncthreads();
    *(bf16x8*)&As[sr][sc8] = av;
    *(bf16x8*)&Bs[sr][sc8] = bv;
    __syncthreads();
    bf16x8 af[2], bf_[2];
    #pragma unroll
    for (int rt = 0; rt < 2; ++rt) af[rt]  = *(bf16x8*)&As[wr + rt * 16 + frow][fkc * 8];
    #pragma unroll
    for (int ct = 0; ct < 2; ++ct) bf_[ct] = *(bf16x8*)&Bs[wc + ct * 16 + frow][fkc * 8];
    #pragma unroll
    for (int rt = 0; rt < 2; ++rt)
      #pragma unroll
      for (int ct = 0; ct < 2; ++ct)
        acc[rt][ct] = __builtin_amdgcn_mfma_f32_16x16x32_bf16(af[rt], bf_[ct], acc[rt][ct], 0, 0, 0);
  }
  #pragma unroll
  for (int rt = 0; rt < 2; ++rt)
    #pragma unroll
    for (int ct = 0; ct < 2; ++ct)
      #pragma unroll
      for (int r = 0; r < 4; ++r){
        int row = m0 + wr + rt * 16 + (lane >> 4) * 4 + r;
        int col = n0 + wc + ct * 16 + (lane & 15);
        float v = acc[rt][ct][r];
        if (HAS_BIAS) v += bias[col];
        if (ACT == 1) v = (v >= 0.f) ? v : 0.2f * v;
        if (HAS_RES) v += res[(size_t)row * N + col];
        if (OUT_BF16) ((u16*)Cout)[(size_t)row * N + col] = f2bf(v);
        else          ((float*)Cout)[(size_t)row * N + col] = v;
      }
}

// ---------------- repack qkv -> per-head panels ----------------
__global__ void repack_kernel(const u16* __restrict__ qkv, u16* __restrict__ Qb,
                              u16* __restrict__ Kb, u16* __restrict__ Vb){
  int idx = blockIdx.x * 256 + threadIdx.x;
  if (idx >= S_TOT * INNERC) return;
  int s = idx / INNERC, hd = idx % INNERC;
  int h = hd >> 6, d = hd & 63;
  const u16* p = qkv + (size_t)s * 3 * INNERC + 3 * hd;
  size_t o = (size_t)h * S_TOT * DHC + (size_t)s * DHC + d;
  Qb[o] = p[0];
  Kb[o] = p[1];
  Vb[o] = p[2];
}

// ---------------- fused attention: 16 q x 1 head per block, 4 waves, split-K LDS ----------------
// NOTE: no min-waves arg — (256,4) clamped VGPR to 64 and spilled the pk arrays
// (74 MB scratch writes/dispatch, r6). ~110 VGPR still gives 4 blocks/CU (<=128 tier).
__global__ __launch_bounds__(256) void attn_kernel(const u16* __restrict__ Qbf,
                                                   const u16* __restrict__ Kbf,
                                                   const u16* __restrict__ Vbf,
                                                   const float* __restrict__ rel_bias,
                                                   const unsigned char* __restrict__ buck,
                                                   const int* __restrict__ topk_p,
                                                   u16* __restrict__ attnout){
  const int sq0 = blockIdx.x * QBLK;
  const int hh  = blockIdx.y;
  const int tid = threadIdx.x;
  const int lane = tid & 63;
  const int wid  = tid >> 6;

  __shared__ u16   score[QBLK][SPA];     // 26.9 KB, reused for both key chunks
  __shared__ u16   Qt_s[QBLK][72];
  __shared__ float qb[QBLK][49];
  __shared__ u16   idxs[4][CAPC];
  __shared__ float pcomp[4][CAPC];

  const u16* Qh = Qbf + (size_t)hh * S_TOT * DHC;
  const u16* Kh = Kbf + (size_t)hh * S_TOT * DHC;
  const u16* Vh = Vbf + (size_t)hh * S_TOT * DHC;

  if (tid < 128){
    int r = tid >> 3, c8 = (tid & 7) * 8;
    *(bf16x8*)&Qt_s[r][c8] = *(const bf16x8*)(Qh + (size_t)(sq0 + r) * DHC + c8);
  }
  __syncthreads();

  for (int i = tid; i < QBLK * 49; i += 256){
    int q = i / 49, nb = i % 49;
    const float* rb = rel_bias + (size_t)nb * DHC;
    float s = 0.f;
    #pragma unroll 8
    for (int d = 0; d < DHC; ++d) s += bf2f(Qt_s[q][d]) * rb[d];
    qb[q][nb] = s;
  }
  __syncthreads();

  const float scale = 0.05103103630798287f; // 384^-0.5
  int kwant = *topk_p;
  if (kwant > S_TOT) kwant = S_TOT;

  // ---- phase 1a: keys [0, 832), 13 tiles per wave ----
  {
    bf16x8 a0 = *(bf16x8*)&Qt_s[lane & 15][(lane >> 4) * 8];
    bf16x8 a1 = *(bf16x8*)&Qt_s[lane & 15][32 + (lane >> 4) * 8];
    for (int t = 0; t < 13; ++t){
      int key = (wid * 13 + t) * 16 + (lane & 15);
      const u16* kp = Kh + (size_t)key * DHC + (lane >> 4) * 8;
      bf16x8 b0 = *(const bf16x8*)kp;
      bf16x8 b1 = *(const bf16x8*)(kp + 32);
      f32x4 c = {};
      c = __builtin_amdgcn_mfma_f32_16x16x32_bf16(a0, b0, c, 0, 0, 0);
      c = __builtin_amdgcn_mfma_f32_16x16x32_bf16(a1, b1, c, 0, 0, 0);
      const unsigned char* bp = buck + (size_t)sq0 * S_TOT + key;
      #pragma unroll
      for (int r = 0; r < 4; ++r){
        int q = (lane >> 4) * 4 + r;
        int bb = bp[(size_t)q * S_TOT];
        score[q][key] = f2bf((c[r] + qb[q][bb]) * scale);
      }
    }
  }
  __syncthreads();

  // ---- phase 2a: pull chunk-A keys into regs (packed q-pairs) ----
  unsigned pk0[25], pk1[25];
  float lm0 = -FLT_MAX, lm1 = -FLT_MAX, lm2 = -FLT_MAX, lm3 = -FLT_MAX;
  const int qw = wid * 4;
  #pragma unroll
  for (int i = 0; i < 13; ++i){
    int col = lane + 64 * i;
    u16 u0 = score[qw + 0][col], u1 = score[qw + 1][col];
    u16 u2 = score[qw + 2][col], u3 = score[qw + 3][col];
    lm0 = fmaxf(lm0, bf2f(u0)); lm1 = fmaxf(lm1, bf2f(u1));
    lm2 = fmaxf(lm2, bf2f(u2)); lm3 = fmaxf(lm3, bf2f(u3));
    pk0[i] = (unsigned)sortkey(u0) | ((unsigned)sortkey(u1) << 16);
    pk1[i] = (unsigned)sortkey(u2) | ((unsigned)sortkey(u3) << 16);
  }
  __syncthreads();

  // ---- phase 1b: keys [832, 1600), 12 tiles per wave ----
  {
    bf16x8 a0 = *(bf16x8*)&Qt_s[lane & 15][(lane >> 4) * 8];
    bf16x8 a1 = *(bf16x8*)&Qt_s[lane & 15][32 + (lane >> 4) * 8];
    for (int t = 0; t < 12; ++t){
      int key = SAK + (wid * 12 + t) * 16 + (lane & 15);
      const u16* kp = Kh + (size_t)key * DHC + (lane >> 4) * 8;
      bf16x8 b0 = *(const bf16x8*)kp;
      bf16x8 b1 = *(const bf16x8*)(kp + 32);
      f32x4 c = {};
      c = __builtin_amdgcn_mfma_f32_16x16x32_bf16(a0, b0, c, 0, 0, 0);
      c = __builtin_amdgcn_mfma_f32_16x16x32_bf16(a1, b1, c, 0, 0, 0);
      const unsigned char* bp = buck + (size_t)sq0 * S_TOT + key;
      #pragma unroll
      for (int r = 0; r < 4; ++r){
        int q = (lane >> 4) * 4 + r;
        int bb = bp[(size_t)q * S_TOT];
        score[q][key - SAK] = f2bf((c[r] + qb[q][bb]) * scale);
      }
    }
  }
  __syncthreads();

  // ---- phase 2b: pull chunk-B keys ----
  #pragma unroll
  for (int i2 = 0; i2 < 12; ++i2){
    int col = lane + 64 * i2;
    u16 u0 = score[qw + 0][col], u1 = score[qw + 1][col];
    u16 u2 = score[qw + 2][col], u3 = score[qw + 3][col];
    lm0 = fmaxf(lm0, bf2f(u0)); lm1 = fmaxf(lm1, bf2f(u1));
    lm2 = fmaxf(lm2, bf2f(u2)); lm3 = fmaxf(lm3, bf2f(u3));
    pk0[13 + i2] = (unsigned)sortkey(u0) | ((unsigned)sortkey(u1) << 16);
    pk1[13 + i2] = (unsigned)sortkey(u2) | ((unsigned)sortkey(u3) << 16);
  }

  // ---- 4-way interleaved max reduce ----
  #pragma unroll
  for (int o = 32; o >= 1; o >>= 1){
    lm0 = fmaxf(lm0, __shfl_xor(lm0, o));
    lm1 = fmaxf(lm1, __shfl_xor(lm1, o));
    lm2 = fmaxf(lm2, __shfl_xor(lm2, o));
    lm3 = fmaxf(lm3, __shfl_xor(lm3, o));
  }
  float mfin[4] = {lm0, lm1, lm2, lm3};

  // ---- 4-way interleaved binary search for kth-largest key ----
  int lo[4] = {0, 0, 0, 0}, hi[4] = {65536, 65536, 65536, 65536};
  for (int it = 0; it < 16; ++it){
    int m0 = (lo[0] + hi[0]) >> 1, m1 = (lo[1] + hi[1]) >> 1;
    int m2 = (lo[2] + hi[2]) >> 1, m3 = (lo[3] + hi[3]) >> 1;
    int c0 = 0, c1 = 0, c2 = 0, c3 = 0;
    #pragma unroll
    for (int i = 0; i < 25; ++i){
      unsigned r0 = pk0[i], r1 = pk1[i];
      c0 += ((int)(r0 & 0xFFFFu) >= m0);
      c1 += ((int)(r0 >> 16)     >= m1);
      c2 += ((int)(r1 & 0xFFFFu) >= m2);
      c3 += ((int)(r1 >> 16)     >= m3);
    }
    #pragma unroll
    for (int o = 32; o >= 1; o >>= 1){
      c0 += __shfl_xor(c0, o); c1 += __shfl_xor(c1, o);
      c2 += __shfl_xor(c2, o); c3 += __shfl_xor(c3, o);
    }
    if (c0 >= kwant) lo[0] = m0; else hi[0] = m0;
    if (c1 >= kwant) lo[1] = m1; else hi[1] = m1;
    if (c2 >= kwant) lo[2] = m2; else hi[2] = m2;
    if (c3 >= kwant) lo[3] = m3; else hi[3] = m3;
  }

  // ---- survivor counts (count >= T), 4-way ----
  int cnt[4];
  {
    int c0 = 0, c1 = 0, c2 = 0, c3 = 0;
    #pragma unroll
    for (int i = 0; i < 25; ++i){
      unsigned r0 = pk0[i], r1 = pk1[i];
      c0 += ((int)(r0 & 0xFFFFu) >= lo[0]);
      c1 += ((int)(r0 >> 16)     >= lo[1]);
      c2 += ((int)(r1 & 0xFFFFu) >= lo[2]);
      c3 += ((int)(r1 >> 16)     >= lo[3]);
    }
    #pragma unroll
    for (int o = 32; o >= 1; o >>= 1){
      c0 += __shfl_xor(c0, o); c1 += __shfl_xor(c1, o);
      c2 += __shfl_xor(c2, o); c3 += __shfl_xor(c3, o);
    }
    cnt[0] = c0; cnt[1] = c1; cnt[2] = c2; cnt[3] = c3;
  }

  // ---- per-query compaction + sparse PV (chunked, exact for any tie count) ----
  #pragma unroll
  for (int qi = 0; qi < 4; ++qi){
    const int Tq = lo[qi];
    const float mq = mfin[qi];
    const int cq = cnt[qi];
    float acc = 0.f, lsum = 0.f;
    bool first = true;
    for (int start = 0; start < cq; start += CAPC){
      int run = 0;
      #pragma unroll
      for (int i = 0; i < 25; ++i){
        unsigned kkp = (qi < 2) ? pk0[i] : pk1[i];
        int key = (qi & 1) ? (int)(kkp >> 16) : (int)(kkp & 0xFFFFu);
        bool sv = (key >= Tq);
        unsigned long long mk = __ballot(sv);
        if (sv){
          int pos = run + __popcll(mk & ((1ull << lane) - 1ull));
          float p = __expf(bf2f(invkey(key)) - mq);
          if (first) lsum += p;
          int rel = pos - start;
          if (rel >= 0 && rel < CAPC){
            int gk = (i < 13) ? (lane + 64 * i) : (SAK + lane + 64 * (i - 13));
            idxs[wid][rel] = (u16)gk;
            pcomp[wid][rel] = p;
          }
        }
        run += __popcll(mk);
      }
      first = false;
      int cn = cq - start; if (cn > CAPC) cn = CAPC;
      for (int j = 0; j < cn; ++j)
        acc += pcomp[wid][j] * bf2f(Vh[(size_t)idxs[wid][j] * DHC + lane]);
    }
    float denom = waveReduceSumF(lsum);
    attnout[(size_t)(sq0 + qw + qi) * INNERC + hh * DHC + lane] = f2bf(acc / denom);
  }
}

extern "C" void kernel_launch(void* const* d_in, const int* in_sizes, int n_in,
                              void* d_out, int out_size, void* d_ws, size_t ws_size,
                              hipStream_t stream) {
  const float* x       = (const float*)d_in[0];
  const float* W_qkv   = (const float*)d_in[1];
  const float* W_o     = (const float*)d_in[2];
  const float* ln1_g   = (const float*)d_in[3];
  const float* ln1_b   = (const float*)d_in[4];
  const float* ln2_g   = (const float*)d_in[5];
  const float* ln2_b   = (const float*)d_in[6];
  const float* rel_bias= (const float*)d_in[7];
  const float* ff_w1   = (const float*)d_in[8];
  const float* ff_b1   = (const float*)d_in[9];
  const float* ff_w2   = (const float*)d_in[10];
  const float* ff_b2   = (const float*)d_in[11];
  const int*   Wp      = (const int*)d_in[13];
  const int*   topk_p  = (const int*)d_in[14];

  float* h = (float*)d_out;   // fp32 residual stream

  char* ws = (char*)d_ws;
  u16* nbf    = (u16*)ws;  ws += (size_t)S_TOT * DIMC * 2;
  u16* qkvbf  = (u16*)ws;  ws += (size_t)S_TOT * 3 * INNERC * 2;
  u16* Qbf    = (u16*)ws;  ws += (size_t)NHC * S_TOT * DHC * 2;
  u16* Kbf    = (u16*)ws;  ws += (size_t)NHC * S_TOT * DHC * 2;
  u16* Vbf    = (u16*)ws;  ws += (size_t)NHC * S_TOT * DHC * 2;
  u16* attnbf = (u16*)ws;  ws += (size_t)S_TOT * INNERC * 2;
  u16* y1bf   = (u16*)ws;  ws += (size_t)S_TOT * HIDC * 2;
  u16* wT     = (u16*)ws;  ws += (size_t)1769472 * 2;
  unsigned char* buck = (unsigned char*)ws; ws += (size_t)S_TOT * S_TOT;

  u16* wqkvT = wT;                 // [1152][384]
  u16* woT   = wT + 442368;        // [384][384]
  u16* w1T   = wT + 589824;        // [1536][384]
  u16* w2T   = wT + 1179648;       // [384][1536]

  buck_kernel<<<S_TOT, 256, 0, stream>>>(Wp, buck);
  copy_kernel<<<(S_TOT * DIMC + 255) / 256, 256, 0, stream>>>(x, h, S_TOT * DIMC);

  for (int l = 0; l < 6; ++l){
    const float* wqkv = W_qkv + (size_t)l * DIMC * 3 * INNERC;
    const float* wo   = W_o   + (size_t)l * INNERC * DIMC;
    const float* w1   = ff_w1 + (size_t)l * DIMC * HIDC;
    const float* w2   = ff_w2 + (size_t)l * HIDC * DIMC;

    TC4Args tc{wqkv, wo, w1, w2, wqkvT, woT, w1T, w2T};
    tconv4_kernel<<<1728, 256, 0, stream>>>(tc);

    ln_kernel<<<S_TOT, 128, 0, stream>>>(h, ln1_g + l * DIMC, ln1_b + l * DIMC, nbf);
    gemm_bf16<0, true, false, false><<<dim3(18, 25), 256, 0, stream>>>(
        nbf, wqkvT, nullptr, nullptr, qkvbf, S_TOT, 3 * INNERC, DIMC);
    repack_kernel<<<(S_TOT * INNERC + 255) / 256, 256, 0, stream>>>(qkvbf, Qbf, Kbf, Vbf);
    attn_kernel<<<dim3(S_TOT / QBLK, NHC), 256, 0, stream>>>(
        Qbf, Kbf, Vbf, rel_bias, buck, topk_p, attnbf);
    gemm_bf16<0, false, false, true><<<dim3(6, 25), 256, 0, stream>>>(
        attnbf, woT, nullptr, h, h, S_TOT, DIMC, INNERC);
    ln_kernel<<<S_TOT, 128, 0, stream>>>(h, ln2_g + l * DIMC, ln2_b + l * DIMC, nbf);
    gemm_bf16<1, true, true, false><<<dim3(24, 25), 256, 0, stream>>>(
        nbf, w1T, ff_b1 + l * HIDC, nullptr, y1bf, S_TOT, HIDC, DIMC);
    gemm_bf16<0, false, true, true><<<dim3(6, 25), 256, 0, stream>>>(
        y1bf, w2T, ff_b2 + l * DIMC, h, h, S_TOT, DIMC, HIDC);
  }
}